// Round 2
// baseline (633.017 us; speedup 1.0000x reference)
//
#include <hip/hip_runtime.h>
#include <math.h>

#define B_ 1024
#define D_ 1024
#define N_ 128
#define PT_ 28
#define KSEL 32            // softmax over top 32 (k=33, last dropped)
#define NOISE_EPS_ 0.01f

// ---------------- Kernel 1a: unique t_embed rows ue[28][1024] (fp32) ---------
// grid (28, 4) x 256 threads. block (s, y) computes ue[s][y*256 + tid].
__global__ __launch_bounds__(256) void embed_kernel(
    const float* __restrict__ w1, const float* __restrict__ b1,
    const float* __restrict__ w2, const float* __restrict__ b2,
    float* __restrict__ ue)
{
    __shared__ float h[D_];
    const int s = blockIdx.x;
    const int tid = threadIdx.x;
    const float sf = (float)s;
    for (int d = tid; d < D_; d += 256) {
        float x = sf * w1[d] + b1[d];          // t @ w1.T + b1  (w1 is [D,1])
        h[d] = x / (1.0f + expf(-x));          // SiLU
    }
    __syncthreads();
    const int i = blockIdx.y * 256 + tid;
    const float4* row = (const float4*)(w2 + (size_t)i * D_);   // w2[i, :]
    float acc = 0.0f;
    for (int d = 0; d < D_ / 4; ++d) {
        float4 u = row[d];
        const int d4 = d * 4;
        acc += h[d4 + 0] * u.x + h[d4 + 1] * u.y + h[d4 + 2] * u.z + h[d4 + 3] * u.w;
    }
    ue[(size_t)s * D_ + i] = acc + b2[i];
}

// ------- Kernel 1b: unique clean logits + noise_std, uclean/unstd[28][128] ---
// grid 28 x 256 threads. thread t: n = t&127, half = t>>7 handles 512 of D.
__global__ __launch_bounds__(256) void gate_precompute_kernel(
    const float* __restrict__ gate_w, const float* __restrict__ gate_b,
    const float* __restrict__ w_noise, const int* __restrict__ timestep,
    const float* __restrict__ ue, float* __restrict__ uclean, float* __restrict__ unstd)
{
    __shared__ float te[D_];
    __shared__ float pc[2][N_];
    __shared__ float pn[2][N_];
    const int s = blockIdx.x;
    const int tid = threadIdx.x;
    for (int d = tid; d < D_; d += 256) te[d] = ue[(size_t)s * D_ + d];
    __syncthreads();
    const int n = tid & (N_ - 1);
    const int half = tid >> 7;
    const int d0 = half * (D_ / 2);
    const float* grow = gate_w + (size_t)n * (D_ + 1) + d0;   // gate_w[n, d0..]
    float cl = 0.0f, nz = 0.0f;
    for (int d = 0; d < D_ / 2; ++d) {
        float tv = te[d0 + d];
        cl += tv * grow[d];
        nz += tv * w_noise[(size_t)(d0 + d) * N_ + n];        // w_noise[d, n]
    }
    pc[half][n] = cl; pn[half][n] = nz;
    __syncthreads();
    if (tid < N_) {
        const int step = timestep[0];
        float cl2 = pc[0][tid] + pc[1][tid]
                  + (float)step * gate_w[(size_t)tid * (D_ + 1) + D_]   // depth col
                  + gate_b[tid];
        uclean[s * N_ + tid] = cl2;
        float nz2 = pn[0][tid] + pn[1][tid];
        float sp = (nz2 > 20.0f) ? nz2 : log1pf(expf(nz2));   // softplus
        unstd[s * N_ + tid] = sp + NOISE_EPS_;
    }
}

// -------- Kernel 2: per-row gating + big masked-scale write -----------------
// grid B x 256 threads; block b writes out0[b, :, :] (128x1024 f32) + out1[b,:]
__global__ __launch_bounds__(256) void out_kernel(
    const float* __restrict__ pe,     // [28,128,1024]
    const float* __restrict__ noise,  // [B,128]
    const int* __restrict__ timestep,
    const float* __restrict__ ue, const float* __restrict__ uclean,
    const float* __restrict__ unstd,
    float* __restrict__ out0, float* __restrict__ out1)
{
    __shared__ float noisy[N_];
    __shared__ float gates[N_];
    __shared__ float inv_sum;
    const int b = blockIdx.x;
    const int tid = threadIdx.x;
    const int tb = timestep[b];
    const int step = timestep[0];

    // out1: t_embed[b,:] = ue[tb,:]
    const float* uer = ue + (size_t)tb * D_;
    for (int i = tid; i < D_; i += 256)
        out1[(size_t)b * D_ + i] = uer[i];

    if (tid < N_) {
        noisy[tid] = uclean[tb * N_ + tid]
                   + noise[(size_t)b * N_ + tid] * unstd[tb * N_ + tid];
    }
    __syncthreads();
    if (tid < N_) {
        const float v = noisy[tid];
        int rank = 0; float mx = -INFINITY;
        for (int m = 0; m < N_; ++m) {
            float u = noisy[m];
            mx = fmaxf(mx, u);
            rank += ((u > v) || (u == v && m < tid)) ? 1 : 0;   // lax.top_k tie-break
        }
        gates[tid] = (rank < KSEL) ? expf(v - mx) : 0.0f;
    }
    __syncthreads();
    if (tid == 0) {
        float s = 0.0f;
        for (int m = 0; m < N_; ++m) s += gates[m];
        inv_sum = 1.0f / s;
    }
    __syncthreads();
    if (tid < N_) gates[tid] *= inv_sum;
    __syncthreads();

    // big write: out0[b,n,d] = prompts[step,n,d] * gates[n], float4 vectorized
    const float4* __restrict__ psrc = (const float4*)(pe + (size_t)step * N_ * D_);
    float4* __restrict__ pdst = (float4*)(out0 + (size_t)b * N_ * D_);
    const int NV = N_ * D_ / 4;                 // 32768 float4 per batch row
    for (int idx = tid; idx < NV; idx += 256) {
        const int n = idx >> 8;                 // 256 float4 per n (D=1024)
        const float g = gates[n];
        float4 o;
        if (g != 0.0f) {
            float4 u = psrc[idx];
            o.x = u.x * g; o.y = u.y * g; o.z = u.z * g; o.w = u.w * g;
        } else {
            o.x = 0.0f; o.y = 0.0f; o.z = 0.0f; o.w = 0.0f;
        }
        pdst[idx] = o;
    }
}

extern "C" void kernel_launch(void* const* d_in, const int* in_sizes, int n_in,
                              void* d_out, int out_size, void* d_ws, size_t ws_size,
                              hipStream_t stream) {
    (void)in_sizes; (void)n_in; (void)out_size; (void)ws_size;
    const float* pe      = (const float*)d_in[0];
    const float* w1      = (const float*)d_in[1];
    const float* b1      = (const float*)d_in[2];
    const float* w2      = (const float*)d_in[3];
    const float* b2      = (const float*)d_in[4];
    const float* gate_w  = (const float*)d_in[5];
    const float* gate_b  = (const float*)d_in[6];
    const float* w_noise = (const float*)d_in[7];
    const float* noise   = (const float*)d_in[8];
    const int*   ts      = (const int*)d_in[9];

    float* ws     = (float*)d_ws;
    float* ue     = ws;                         // 28*1024 fp32
    float* uclean = ue + PT_ * D_;              // 28*128
    float* unstd  = uclean + PT_ * N_;          // 28*128

    float* out0 = (float*)d_out;                       // [B,N,D]
    float* out1 = out0 + (size_t)B_ * N_ * D_;         // [B,D]

    hipLaunchKernelGGL(embed_kernel, dim3(PT_, 4), dim3(256), 0, stream,
                       w1, b1, w2, b2, ue);
    hipLaunchKernelGGL(gate_precompute_kernel, dim3(PT_), dim3(256), 0, stream,
                       gate_w, gate_b, w_noise, ts, ue, uclean, unstd);
    hipLaunchKernelGGL(out_kernel, dim3(B_), dim3(256), 0, stream,
                       pe, noise, ts, ue, uclean, unstd, out0, out1);
}